// Round 14
// baseline (303.748 us; speedup 1.0000x reference)
//
#include <hip/hip_runtime.h>

// Problem constants (fixed by setup_inputs)
#define N_IN   100000
#define N_OUT  25000
#define KNN    9
#define N_EL   200000
#define BB     4
#define C_IN   8
#define C_OUT  16
#define M_EDGE (N_OUT * KNN)    // 225000
#define MP     225024           // M_EDGE padded to x64 (h_t row stride)

#define SOP  65                 // padded stride for s_out
// einsum kernel geometry: 7 dsts = 63 edges per block; wave w handles jq=w
#define DPB2 7
#define EPB2 (DPB2 * KNN)       // 63
// fused fallback geometry (R13)
#define DPBF 14
#define EPBF (DPBF * KNN)       // 126
#define HST  17

// ---------------------------------------------------------------------------
// Phase A: element MLP -> el_w (N_EL,3) scatter-added into node_w.
// ---------------------------------------------------------------------------
__global__ void __launch_bounds__(256) elem_kernel(
    const int*   __restrict__ el,   // (N_EL,3)
    const float* __restrict__ dp,   // (N_IN,2)
    const float* __restrict__ w0, const float* __restrict__ b0,
    const float* __restrict__ w1, const float* __restrict__ b1,
    const float* __restrict__ w2, const float* __restrict__ b2,
    const float* __restrict__ w3, const float* __restrict__ b3,
    float* __restrict__ node_w)
{
    int e = blockIdx.x * 256 + threadIdx.x;
    if (e >= N_EL) return;
    int i0 = el[e*3+0], i1 = el[e*3+1], i2 = el[e*3+2];
    float2 p0 = ((const float2*)dp)[i0];
    float2 p1 = ((const float2*)dp)[i1];
    float2 p2 = ((const float2*)dp)[i2];
    float p[6] = { p0.x, p0.y, p1.x, p1.y, p2.x, p2.y };

    float h[8], h2[8];
#pragma unroll
    for (int k = 0; k < 8; ++k) {
        float t = b0[k];
#pragma unroll
        for (int j = 0; j < 6; ++j) t = fmaf(p[j], w0[j*8+k], t);
        h[k] = 1.f / (1.f + __expf(-t));
    }
#pragma unroll
    for (int k = 0; k < 8; ++k) {
        float t = b1[k];
#pragma unroll
        for (int j = 0; j < 8; ++j) t = fmaf(h[j], w1[j*8+k], t);
        h2[k] = 1.f / (1.f + __expf(-t));
    }
#pragma unroll
    for (int k = 0; k < 8; ++k) {
        float t = b2[k];
#pragma unroll
        for (int j = 0; j < 8; ++j) t = fmaf(h2[j], w2[j*8+k], t);
        h[k] = 1.f / (1.f + __expf(-t));
    }
    float o[3];
#pragma unroll
    for (int k = 0; k < 3; ++k) {
        float t = b3[k];
#pragma unroll
        for (int j = 0; j < 8; ++j) t = fmaf(h[j], w3[j*3+k], t);
        o[k] = 1.f / (1.f + __expf(-t));
    }
    atomicAdd(&node_w[i0], o[0]);
    atomicAdd(&node_w[i1], o[1]);
    atomicAdd(&node_w[i2], o[2]);
}

// ---------------------------------------------------------------------------
// Prep: zero node_w; transpose features -> feat_t[n][i*4+b]; transpose
// w_out (16,128) -> w_out_t[col][k] (k-contiguous -> s_load_dwordx16).
// ---------------------------------------------------------------------------
__global__ void __launch_bounds__(256) prep_kernel(
    const float* __restrict__ f, float* __restrict__ ft,
    const float* __restrict__ w_out, float* __restrict__ w_out_t,
    float* __restrict__ node_w)
{
    int n = blockIdx.x * 256 + threadIdx.x;
    if (n < C_IN * C_OUT * 16)                       // 2048
        w_out_t[n] = w_out[(n & 15) * 128 + (n >> 4)];
    if (n >= N_IN) return;
    node_w[n] = 0.f;
    float v[32];
#pragma unroll
    for (int c = 0; c < 32; ++c) v[c] = f[c * N_IN + n];   // coalesced per c
    float4* dst = (float4*)(ft + (size_t)n * 32);
#pragma unroll
    for (int q = 0; q < 8; ++q)                      // slot i*4+b <- c=b*8+i
        dst[q] = make_float4(v[q], v[8+q], v[16+q], v[24+q]);
}

// ---------------------------------------------------------------------------
// E1: per-edge SIREN -> h_t[k][e] (transposed: both store here and load in
// E2 are fully coalesced). Pure VALU, no LDS, no gather chains.
// ---------------------------------------------------------------------------
__global__ void __launch_bounds__(256) siren_kernel(
    const float* __restrict__ dp,      // (N_IN,2)
    const float* __restrict__ rp,      // (N_OUT,2)
    const int*   __restrict__ src_idx, // (M)
    const float* __restrict__ w_in,    // (2,16)
    const float* __restrict__ b_in,    // (16)
    const float* __restrict__ wh,      // (4,16,16)
    const float* __restrict__ bh,      // (4,16)
    float* __restrict__ h_t)           // [16][MP]
{
    int e = blockIdx.x * 256 + threadIdx.x;
    if (e >= M_EDGE) return;
    const int dst = e / KNN;
    const int src = src_idx[e];
    const float2 rpt = ((const float2*)rp)[dst];
    const float2 dpt = ((const float2*)dp)[src];
    const float lx = rpt.x - dpt.x;
    const float ly = rpt.y - dpt.y;

    float h[16];
#pragma unroll
    for (int k = 0; k < 16; ++k)
        h[k] = __sinf(fmaf(lx, w_in[k], fmaf(ly, w_in[16+k], b_in[k])));
#pragma unroll
    for (int L = 0; L < 4; ++L) {
        float h2[16];
#pragma unroll
        for (int k = 0; k < 16; ++k) {
            float t = bh[L*16 + k];
#pragma unroll
            for (int j = 0; j < 16; ++j)
                t = fmaf(h[j], wh[L*256 + j*16 + k], t);
            h2[k] = t;
        }
#pragma unroll
        for (int k = 0; k < 16; ++k) h[k] = __sinf(h2[k]);
    }
#pragma unroll
    for (int k = 0; k < 16; ++k) h_t[k * MP + e] = h[k];   // coalesced per k
}

// ---------------------------------------------------------------------------
// E2: einsum. 4 threads/edge (one col-quad each) -> 900K threads, occupancy
// cap lifted to full. Wave w of each block handles jq=w: weight addresses are
// wave-uniform -> s_load (SMEM pipe, no VALU/LDS cost). hh[16] loaded once
// from h_t (coalesced) into registers; live set ~45 VGPR fits the compiler's
// 64-VGPR/8-wave allocation target -> nothing demoted. LDS = s_out only.
// ---------------------------------------------------------------------------
__global__ void __launch_bounds__(256) einsum_kernel(
    const float* __restrict__ feat_t,  // [N_IN][32] i-major
    const int*   __restrict__ src_idx, // (M)
    const float* __restrict__ node_w,  // (N_IN)
    const float* __restrict__ h_t,     // [16][MP]
    const float* __restrict__ w_out_t, // (128,16) k-contiguous
    const float* __restrict__ b_out,   // (128)
    float* __restrict__ out)           // (B, C_OUT, N_OUT) flat
{
    __shared__ float s_out[DPB2 * SOP];                 // 1.8 KB
    const int tid  = threadIdx.x;
    const int lane = tid & 63;
    const int jq   = tid >> 6;                          // wave-uniform

    for (int i = tid; i < DPB2 * SOP; i += 256) s_out[i] = 0.f;
    __syncthreads();

    const int  dst0  = blockIdx.x * DPB2;
    const int  e_loc = (lane < EPB2) ? lane : 0;
    const int  dst   = dst0 + e_loc / KNN;
    const bool valid = (lane < EPB2) && (dst < N_OUT);
    const int  ce    = valid ? (blockIdx.x * EPB2 + e_loc) : 0;
    const int  src   = src_idx[ce];
    const float scale = valid ? node_w[src] * 0.125f : 0.f;

    float hh[16];
#pragma unroll
    for (int k = 0; k < 16; ++k) hh[k] = h_t[k * MP + ce];  // coalesced

    const float4* fp4 = (const float4*)(feat_t + (size_t)src * 32);
    float acc[16];
#pragma unroll
    for (int t = 0; t < 16; ++t) acc[t] = 0.f;
#pragma unroll
    for (int i = 0; i < C_IN; ++i) {
        const float4 gb = fp4[i];
#pragma unroll
        for (int jj = 0; jj < 4; ++jj) {
            const int col = i*16 + jq*4 + jj;           // wave-uniform
            float f = b_out[col];
#pragma unroll
            for (int k = 0; k < 16; ++k)
                f = fmaf(hh[k], w_out_t[col*16 + k], f);
            f *= scale;
            acc[0*4+jj] = fmaf(f, gb.x, acc[0*4+jj]);
            acc[1*4+jj] = fmaf(f, gb.y, acc[1*4+jj]);
            acc[2*4+jj] = fmaf(f, gb.z, acc[2*4+jj]);
            acc[3*4+jj] = fmaf(f, gb.w, acc[3*4+jj]);
        }
    }
    const int ldst = e_loc / KNN;
#pragma unroll
    for (int b = 0; b < BB; ++b)
#pragma unroll
        for (int jj = 0; jj < 4; ++jj)
            atomicAdd(&s_out[ldst * SOP + b*16 + jq*4 + jj], acc[b*4+jj]);
    __syncthreads();

    // write-out: 7*64 = 448 values
    for (int i = tid; i < DPB2 * 64; i += 256) {
        const int d = i % DPB2;
        const int c = i / DPB2;
        const int g = dst0 + d;
        if (g < N_OUT) out[(size_t)c * N_OUT + g] = s_out[d * SOP + c];
    }
}

// ---------------------------------------------------------------------------
// Fallback (ws too small): R13's fused two-phase edge kernel, raw arrays.
// ---------------------------------------------------------------------------
__global__ void __launch_bounds__(256, 6) edge_fused_kernel(
    const float* __restrict__ feat, const float* __restrict__ dp,
    const float* __restrict__ rp, const int* __restrict__ src_idx,
    const float* __restrict__ node_w, const float* __restrict__ w_in,
    const float* __restrict__ b_in, const float* __restrict__ wh,
    const float* __restrict__ bh, const float* __restrict__ w_out,
    const float* __restrict__ b_out, float* __restrict__ out)
{
    __shared__ float s_out[DPBF * SOP];
    __shared__ float h_lds[EPBF * HST];
    __shared__ int   s_src[EPBF];
    __shared__ float s_scale[EPBF];
    const int tid = threadIdx.x;
    for (int i = tid; i < DPBF * SOP; i += 256) s_out[i] = 0.f;
    if (tid < EPBF) {
        const int eg = blockIdx.x * EPBF + tid;
        const int dst = blockIdx.x * DPBF + tid / KNN;
        const bool valid = (dst < N_OUT);
        const int ce = valid ? eg : 0;
        const int src = src_idx[ce];
        s_src[tid] = src;
        s_scale[tid] = valid ? node_w[src] * 0.125f : 0.f;
        const float2 rpt = ((const float2*)rp)[valid ? dst : 0];
        const float2 dpt = ((const float2*)dp)[src];
        const float lx = rpt.x - dpt.x, ly = rpt.y - dpt.y;
        float h[16];
#pragma unroll
        for (int k = 0; k < 16; ++k)
            h[k] = __sinf(fmaf(lx, w_in[k], fmaf(ly, w_in[16+k], b_in[k])));
#pragma unroll
        for (int L = 0; L < 4; ++L) {
            float h2[16];
#pragma unroll
            for (int k = 0; k < 16; ++k) {
                float t = bh[L*16 + k];
#pragma unroll
                for (int j = 0; j < 16; ++j) t = fmaf(h[j], wh[L*256 + j*16 + k], t);
                h2[k] = t;
            }
#pragma unroll
            for (int k = 0; k < 16; ++k) h[k] = __sinf(h2[k]);
        }
#pragma unroll
        for (int k = 0; k < 16; ++k) h_lds[tid * HST + k] = h[k];
    }
    __syncthreads();
#pragma unroll 1
    for (int r = 0; r < 2; ++r) {
        const int item = tid + r * 256;
        const int e = item & 127;
        const int jq = __builtin_amdgcn_readfirstlane(item >> 7);
        if (e < EPBF) {
            const int src = s_src[e];
            const float scale = s_scale[e];
            float hh[16];
#pragma unroll
            for (int k = 0; k < 16; ++k) hh[k] = h_lds[e * HST + k];
            float acc[16];
#pragma unroll
            for (int t = 0; t < 16; ++t) acc[t] = 0.f;
#pragma unroll
            for (int i = 0; i < C_IN; ++i) {
                float4 gb = make_float4(feat[(0*8+i)*N_IN+src], feat[(1*8+i)*N_IN+src],
                                        feat[(2*8+i)*N_IN+src], feat[(3*8+i)*N_IN+src]);
#pragma unroll
                for (int jj = 0; jj < 4; ++jj) {
                    const int col = i*16 + jq*4 + jj;
                    float f = b_out[col];
#pragma unroll
                    for (int k = 0; k < 16; ++k) f = fmaf(hh[k], w_out[k*128 + col], f);
                    f *= scale;
                    acc[0*4+jj] = fmaf(f, gb.x, acc[0*4+jj]);
                    acc[1*4+jj] = fmaf(f, gb.y, acc[1*4+jj]);
                    acc[2*4+jj] = fmaf(f, gb.z, acc[2*4+jj]);
                    acc[3*4+jj] = fmaf(f, gb.w, acc[3*4+jj]);
                }
            }
            const int ldst = e / KNN;
#pragma unroll
            for (int b = 0; b < BB; ++b)
#pragma unroll
                for (int jj = 0; jj < 4; ++jj)
                    atomicAdd(&s_out[ldst * SOP + b*16 + jq*4 + jj], acc[b*4+jj]);
        }
    }
    __syncthreads();
    const int dst0 = blockIdx.x * DPBF;
#pragma unroll 1
    for (int i = tid; i < DPBF * 64; i += 256) {
        const int d = i % DPBF, c = i / DPBF;
        const int g = dst0 + d;
        if (g < N_OUT) out[(size_t)c * N_OUT + g] = s_out[d * SOP + c];
    }
}

// ---------------------------------------------------------------------------
extern "C" void kernel_launch(void* const* d_in, const int* in_sizes, int n_in,
                              void* d_out, int out_size, void* d_ws, size_t ws_size,
                              hipStream_t stream)
{
    (void)in_sizes; (void)n_in; (void)out_size;
    const float* features = (const float*)d_in[0];
    const float* dp       = (const float*)d_in[1];
    const float* rp       = (const float*)d_in[2];
    const int*   src_idx  = (const int*)d_in[4];   // d_in[3] (eval_idx_dst) unused
    const int*   el       = (const int*)d_in[5];
    const float* w_in     = (const float*)d_in[6];
    const float* b_in     = (const float*)d_in[7];
    const float* wh       = (const float*)d_in[8];
    const float* bh       = (const float*)d_in[9];
    const float* w_out    = (const float*)d_in[10];
    const float* b_out    = (const float*)d_in[11];
    const float* wm_w0    = (const float*)d_in[12];
    const float* wm_b0    = (const float*)d_in[13];
    const float* wm_w1    = (const float*)d_in[14];
    const float* wm_b1    = (const float*)d_in[15];
    const float* wm_w2    = (const float*)d_in[16];
    const float* wm_b2    = (const float*)d_in[17];
    const float* wm_w3    = (const float*)d_in[18];
    const float* wm_b3    = (const float*)d_in[19];
    float* out = (float*)d_out;

    // workspace: [node_w][feat_t][w_out_t][h_t], 512B-aligned sections
    size_t off0 = 0;
    size_t off1 = (off0 + (size_t)N_IN * sizeof(float) + 511) & ~(size_t)511;
    size_t off2 = (off1 + (size_t)N_IN * 32 * sizeof(float) + 511) & ~(size_t)511;
    size_t off3 = (off2 + (size_t)2048 * sizeof(float) + 511) & ~(size_t)511;
    size_t need = off3 + (size_t)16 * MP * sizeof(float);
    float* node_w  = (float*)((char*)d_ws + off0);
    float* feat_t  = (float*)((char*)d_ws + off1);
    float* w_out_t = (float*)((char*)d_ws + off2);
    float* h_t     = (float*)((char*)d_ws + off3);
    const bool use_t = (ws_size >= need);

    if (use_t) {
        prep_kernel<<<(N_IN + 255) / 256, 256, 0, stream>>>(
            features, feat_t, w_out, w_out_t, node_w);
        elem_kernel<<<(N_EL + 255) / 256, 256, 0, stream>>>(
            el, dp, wm_w0, wm_b0, wm_w1, wm_b1, wm_w2, wm_b2, wm_w3, wm_b3, node_w);
        siren_kernel<<<(M_EDGE + 255) / 256, 256, 0, stream>>>(
            dp, rp, src_idx, w_in, b_in, wh, bh, h_t);
        einsum_kernel<<<(N_OUT + DPB2 - 1) / DPB2, 256, 0, stream>>>(
            feat_t, src_idx, node_w, h_t, w_out_t, b_out, out);
    } else {
        hipMemsetAsync(node_w, 0, (size_t)N_IN * sizeof(float), stream);
        elem_kernel<<<(N_EL + 255) / 256, 256, 0, stream>>>(
            el, dp, wm_w0, wm_b0, wm_w1, wm_b1, wm_w2, wm_b2, wm_w3, wm_b3, node_w);
        edge_fused_kernel<<<(N_OUT + DPBF - 1) / DPBF, 256, 0, stream>>>(
            features, dp, rp, src_idx, node_w,
            w_in, b_in, wh, bh, w_out, b_out, out);
    }
}